// Round 4
// baseline (302.917 us; speedup 1.0000x reference)
//
#include <hip/hip_runtime.h>
#include <float.h>
#include <math.h>

#define N_ROWS 4096
#define M_TGT  65536
#define DDIM   256

// ---------------------------------------------------------------------------
// Shared types/helpers
// ---------------------------------------------------------------------------
typedef short bf16x8 __attribute__((ext_vector_type(8)));
typedef float f32x4 __attribute__((ext_vector_type(4)));
typedef unsigned short ushort4_t __attribute__((ext_vector_type(4)));

__device__ inline unsigned short f2bf(float f) {
  union { float f; unsigned u; } c; c.f = f;
  unsigned u = c.u;
  unsigned r = (u + 0x7FFFu + ((u >> 16) & 1u)) >> 16;  // RNE
  return (unsigned short)r;
}

__device__ inline void gload_lds16(const void* g, void* l) {
  __builtin_amdgcn_global_load_lds(
      (const __attribute__((address_space(1))) void*)g,
      (__attribute__((address_space(3))) void*)l, 16, 0, 0);
}

// ---------------------------------------------------------------------------
// Fused fp32->bf16 convert + row norm. One wave per row.
// ---------------------------------------------------------------------------
__global__ __launch_bounds__(256) void conv_norm_kernel(
    const float* __restrict__ src, unsigned short* __restrict__ dst,
    float* __restrict__ nrm, int nrows) {
  int wave = threadIdx.x >> 6;
  int lane = threadIdx.x & 63;
  int row  = blockIdx.x * 4 + wave;
  if (row >= nrows) return;
  const float* s = src + (size_t)row * DDIM;
  float4 v = *(const float4*)(s + lane * 4);
  float ss = v.x * v.x + v.y * v.y + v.z * v.z + v.w * v.w;
  ushort4_t o;
  o[0] = f2bf(v.x); o[1] = f2bf(v.y); o[2] = f2bf(v.z); o[3] = f2bf(v.w);
  *(ushort4_t*)(dst + (size_t)row * DDIM + lane * 4) = o;
  #pragma unroll
  for (int off = 32; off > 0; off >>= 1) ss += __shfl_xor(ss, off, 64);
  if (lane == 0) nrm[row] = ss;
}

// ---------------------------------------------------------------------------
// bf16 MFMA screening GEMM — pipelined 256x256 tile, 8 waves (2Mx4N), BK=32.
// Depth-2 K-tile prefetch with counted vmcnt (never 0 in steady state),
// raw s_barrier (no vmcnt drain), setprio around the 32-MFMA cluster.
// LDS: 2 buffers x (A 256x32 + B 256x32) bf16 = 64 KB.
// Swizzle: 64B rows = 4x16B slots; phys slot p = logical cg ^ ((row>>1)&3)
// -> 2-way bank aliasing (free). Stage source pre-permuted (rule 21).
// Output: per (row, 128-col group) min of (tn[col] - 2*dot) into blocked
// bmv2[cb][row][2] (coalesced 2KB/block writes, no write amplification).
// ---------------------------------------------------------------------------
#define TBM 256
#define TBN 256
#define TBK 32
#define NKT 8                      // 256/32 K-tiles
#define NCB 512                    // 128-col groups
#define MARGIN 1.5f

#define STAGE(T)                                                         \
  { const int b_ = (T) & 1;                                              \
    _Pragma("unroll")                                                    \
    for (int i = 0; i < 2; ++i) {                                        \
      gload_lds16(xb + (size_t)(row0 + arow[i]) * DDIM + (T) * 32 + asrc[i], \
                  (char*)&sAB[b_][0][0] + (i * 512 + tid) * 16);         \
      gload_lds16(tb + (size_t)(col0 + arow[i]) * DDIM + (T) * 32 + asrc[i], \
                  (char*)&sAB[b_][1][0] + (i * 512 + tid) * 16);         \
    } }

#define KTILE(T, VN)                                                     \
  { asm volatile("s_waitcnt vmcnt(" #VN ")" ::: "memory");               \
    __builtin_amdgcn_sched_barrier(0);                                   \
    __builtin_amdgcn_s_barrier();                                        \
    const int b_ = (T) & 1;                                              \
    bf16x8 af[8]; bf16x8 bfr[4];                                         \
    _Pragma("unroll")                                                    \
    for (int m = 0; m < 8; ++m) {                                        \
      int r = wr * 128 + m * 16 + ln;                                    \
      int p = cg ^ ((r >> 1) & 3);                                       \
      af[m] = *(const bf16x8*)((const char*)&sAB[b_][0][0] + r * 64 + p * 16); \
    }                                                                    \
    _Pragma("unroll")                                                    \
    for (int n = 0; n < 4; ++n) {                                        \
      int r = wc * 64 + n * 16 + ln;                                     \
      int p = cg ^ ((r >> 1) & 3);                                       \
      bfr[n] = *(const bf16x8*)((const char*)&sAB[b_][1][0] + r * 64 + p * 16); \
    }                                                                    \
    asm volatile("s_waitcnt lgkmcnt(0)" ::: "memory");                   \
    __builtin_amdgcn_sched_barrier(0);                                   \
    __builtin_amdgcn_s_barrier();                                        \
    if ((T) + 2 < NKT) STAGE((T) + 2);                                   \
    __builtin_amdgcn_s_setprio(1);                                       \
    _Pragma("unroll")                                                    \
    for (int m = 0; m < 8; ++m)                                          \
      _Pragma("unroll")                                                  \
      for (int n = 0; n < 4; ++n)                                        \
        acc[m][n] = __builtin_amdgcn_mfma_f32_16x16x32_bf16(             \
            af[m], bfr[n], acc[m][n], 0, 0, 0);                          \
    __builtin_amdgcn_s_setprio(0);                                       \
  }

__global__ __launch_bounds__(512, 2) void nn_gemm_bf16(
    const unsigned short* __restrict__ xb, const unsigned short* __restrict__ tb,
    const float* __restrict__ tn, float* __restrict__ bmv2) {
  __shared__ __align__(16) unsigned short sAB[2][2][TBM * TBK];  // 64 KB

  const int tid  = threadIdx.x;
  const int lane = tid & 63;
  const int wid  = tid >> 6;        // 0..7
  const int wr   = wid >> 2;        // 0..1 (M halves)
  const int wc   = wid & 3;         // 0..3 (N quarters)
  const int ln   = lane & 15;
  const int cg   = lane >> 4;

  // XCD-aware, B-panel-reuse ordering: 4096 = 8 xcd * (16 rb * 32 cb)
  const int bid = blockIdx.x;
  const int xcd = bid & 7;
  const int wgi = bid >> 3;
  const int rb  = wgi & 15;                  // fastest: reuse B col-panel in L2
  const int cb  = xcd * 32 + (wgi >> 4);     // 0..255
  const int row0 = rb * TBM;
  const int col0 = cb * TBN;

  // early tn loads (oldest vmcnt entries, drained by first counted wait)
  float tnc[4];
  #pragma unroll
  for (int n = 0; n < 4; ++n)
    tnc[n] = tn[col0 + wc * 64 + n * 16 + ln];

  // staging map: chunk q = i*512 + tid -> row = q>>2, phys slot = q&3,
  // logical slot s = (q&3) ^ ((row>>1)&3); source k-offset = s*8
  int arow[2], asrc[2];
  #pragma unroll
  for (int i = 0; i < 2; ++i) {
    int q = i * 512 + tid;
    int r = q >> 2;
    arow[i] = r;
    asrc[i] = ((q & 3) ^ ((r >> 1) & 3)) * 8;
  }

  f32x4 acc[8][4];
  const f32x4 zero = {0.0f, 0.0f, 0.0f, 0.0f};
  #pragma unroll
  for (int m = 0; m < 8; ++m)
    #pragma unroll
    for (int n = 0; n < 4; ++n) acc[m][n] = zero;

  // prologue: stage K-tiles 0 and 1
  STAGE(0);
  STAGE(1);

  KTILE(0, 4);
  KTILE(1, 4);
  KTILE(2, 4);
  KTILE(3, 4);
  KTILE(4, 4);
  KTILE(5, 4);
  KTILE(6, 4);
  KTILE(7, 0);

  // ---- epilogue: per-row min of (tn[col] - 2*dot) per 128-col group ----
  __syncthreads();                       // safe to reuse LDS
  float* emin = (float*)&sAB[0][0][0];   // [4 wc][256 rows]

  #pragma unroll
  for (int m = 0; m < 8; ++m) {
    float bv[4];
    #pragma unroll
    for (int j = 0; j < 4; ++j) bv[j] = FLT_MAX;
    #pragma unroll
    for (int n = 0; n < 4; ++n)
      #pragma unroll
      for (int j = 0; j < 4; ++j)
        bv[j] = fminf(bv[j], tnc[n] - 2.0f * acc[m][n][j]);
    #pragma unroll
    for (int off = 1; off < 16; off <<= 1)
      #pragma unroll
      for (int j = 0; j < 4; ++j)
        bv[j] = fminf(bv[j], __shfl_xor(bv[j], off, 64));
    if (ln == 0) {
      int rbase = wr * 128 + m * 16 + cg * 4;
      #pragma unroll
      for (int j = 0; j < 4; ++j)
        emin[wc * 256 + rbase + j] = bv[j];
    }
  }
  __syncthreads();
  if (tid < 256) {
    float g0 = fminf(emin[0 * 256 + tid], emin[1 * 256 + tid]);
    float g1 = fminf(emin[2 * 256 + tid], emin[3 * 256 + tid]);
    float2 o; o.x = g0; o.y = g1;
    *(float2*)&bmv2[((size_t)cb * N_ROWS + row0 + tid) * 2] = o;
  }
}

// ---------------------------------------------------------------------------
// Per-row candidate selection + exact fp32 verification.
// ---------------------------------------------------------------------------
__global__ __launch_bounds__(256) void nn_exact(
    const float* __restrict__ x, const float* __restrict__ t,
    const float* __restrict__ xn, const float* __restrict__ tn,
    const float* __restrict__ bmv2, float* __restrict__ out) {
  __shared__ float sv[NCB];
  __shared__ int   clist[NCB];
  __shared__ int   cnt;
  __shared__ float wmin[4];
  __shared__ float rv[256];
  __shared__ int   ri[256];

  const int row = blockIdx.x;
  const int tid = threadIdx.x;

  if (tid == 0) cnt = 0;
  float lmin = FLT_MAX;
  {
    // tid in 0..255 maps to 256-col block e2 = tid (2 groups each)
    float2 v = *(const float2*)&bmv2[((size_t)tid * N_ROWS + row) * 2];
    sv[2 * tid]     = v.x;
    sv[2 * tid + 1] = v.y;
    lmin = fminf(v.x, v.y);
  }
  #pragma unroll
  for (int off = 32; off > 0; off >>= 1) lmin = fminf(lmin, __shfl_xor(lmin, off, 64));
  if ((tid & 63) == 0) wmin[tid >> 6] = lmin;
  __syncthreads();
  const float g = fminf(fminf(wmin[0], wmin[1]), fminf(wmin[2], wmin[3]));

  #pragma unroll
  for (int e = tid; e < NCB; e += 256) {
    if (sv[e] <= g + MARGIN) {
      int p = atomicAdd(&cnt, 1);
      clist[p] = e;
    }
  }
  __syncthreads();
  const int nc = cnt;

  float best = FLT_MAX;
  int   bidx = 0x7FFFFFFF;
  const float xnr = xn[row];
  const float* xrow = x + (size_t)row * DDIM;

  for (int ci = 0; ci < nc; ci += 2) {
    int slot = ci + (tid >> 7);
    if (slot < nc) {
      int col = clist[slot] * 128 + (tid & 127);
      const float* trow = t + (size_t)col * DDIM;
      float acc = 0.0f;
      for (int kq = 0; kq < DDIM; kq += 4) {
        float4 xv = *(const float4*)(xrow + kq);
        float4 tv = *(const float4*)(trow + kq);
        acc = fmaf(xv.x, tv.x, acc);
        acc = fmaf(xv.y, tv.y, acc);
        acc = fmaf(xv.z, tv.z, acc);
        acc = fmaf(xv.w, tv.w, acc);
      }
      float d2 = xnr + tn[col] - 2.0f * acc;
      if (d2 < best || (d2 == best && col < bidx)) { best = d2; bidx = col; }
    }
  }
  rv[tid] = best; ri[tid] = bidx;
  __syncthreads();
  for (int s = 128; s >= 1; s >>= 1) {
    if (tid < s) {
      float vo = rv[tid + s]; int io = ri[tid + s];
      if (vo < rv[tid] || (vo == rv[tid] && io < ri[tid])) { rv[tid] = vo; ri[tid] = io; }
    }
    __syncthreads();
  }
  if (tid == 0) {
    out[row] = sqrtf(fmaxf(rv[0], 0.0f));
    out[N_ROWS + row] = (float)ri[0];
  }
}

// ---------------------------------------------------------------------------
// Fallback fp32 path (if ws too small) — round-1 proven
// ---------------------------------------------------------------------------
#define BM 64
#define BN 64
#define KC 16
#define S_STRIPS 32
#define PADM 68

__global__ __launch_bounds__(256) void norms_kernel_fb(
    const float* __restrict__ x, const float* __restrict__ t,
    float* __restrict__ xn, float* __restrict__ tn) {
  int wave = threadIdx.x >> 6;
  int lane = threadIdx.x & 63;
  int row  = blockIdx.x * 4 + wave;
  const float* src; float* dst;
  if (row < N_ROWS) { src = x + (size_t)row * DDIM; dst = xn + row; }
  else {
    int r = row - N_ROWS;
    if (r >= M_TGT) return;
    src = t + (size_t)r * DDIM; dst = tn + r;
  }
  float4 v = *(const float4*)(src + lane * 4);
  float s = v.x * v.x + v.y * v.y + v.z * v.z + v.w * v.w;
  #pragma unroll
  for (int off = 32; off > 0; off >>= 1) s += __shfl_xor(s, off, 64);
  if (lane == 0) *dst = s;
}

__global__ __launch_bounds__(256) void nn_main_fb(
    const float* __restrict__ x, const float* __restrict__ t,
    const float* __restrict__ xn, const float* __restrict__ tn,
    float* __restrict__ pmin, int* __restrict__ pidx) {
  __shared__ float sx[KC][PADM];
  __shared__ float st[KC][PADM];
  const int tid = threadIdx.x;
  const int rb = blockIdx.x;
  const int strip = blockIdx.y;
  const int tx = tid & 15, ty = tid >> 4;
  const int row0 = rb * BM;
  const int col_start = strip * (M_TGT / S_STRIPS);
  const int ntiles = (M_TGT / S_STRIPS) / BN;
  const int srow = tid >> 2;
  const int kq = (tid & 3) * 4;

  float runMin[4]; int runIdx[4];
  #pragma unroll
  for (int r = 0; r < 4; ++r) { runMin[r] = FLT_MAX; runIdx[r] = 0; }
  float xnr[4];
  #pragma unroll
  for (int r = 0; r < 4; ++r) xnr[r] = xn[row0 + ty * 4 + r];

  for (int tile = 0; tile < ntiles; ++tile) {
    const int cbk = col_start + tile * BN;
    float acc[4][4];
    #pragma unroll
    for (int r = 0; r < 4; ++r)
      #pragma unroll
      for (int c = 0; c < 4; ++c) acc[r][c] = 0.0f;
    #pragma unroll 1
    for (int kc = 0; kc < DDIM; kc += KC) {
      float4 xv = *(const float4*)(x + (size_t)(row0 + srow) * DDIM + kc + kq);
      float4 tv = *(const float4*)(t + (size_t)(cbk + srow) * DDIM + kc + kq);
      __syncthreads();
      sx[kq + 0][srow] = xv.x; sx[kq + 1][srow] = xv.y;
      sx[kq + 2][srow] = xv.z; sx[kq + 3][srow] = xv.w;
      st[kq + 0][srow] = tv.x; st[kq + 1][srow] = tv.y;
      st[kq + 2][srow] = tv.z; st[kq + 3][srow] = tv.w;
      __syncthreads();
      #pragma unroll
      for (int k = 0; k < KC; ++k) {
        float4 xa = *(const float4*)&sx[k][ty * 4];
        float4 tb2 = *(const float4*)&st[k][tx * 4];
        float xr[4] = {xa.x, xa.y, xa.z, xa.w};
        float tc[4] = {tb2.x, tb2.y, tb2.z, tb2.w};
        #pragma unroll
        for (int r = 0; r < 4; ++r)
          #pragma unroll
          for (int c = 0; c < 4; ++c)
            acc[r][c] = fmaf(xr[r], tc[c], acc[r][c]);
      }
    }
    #pragma unroll
    for (int r = 0; r < 4; ++r)
      #pragma unroll
      for (int c = 0; c < 4; ++c) {
        int col = cbk + tx * 4 + c;
        float d2 = xnr[r] + tn[col] - 2.0f * acc[r][c];
        if (d2 < runMin[r]) { runMin[r] = d2; runIdx[r] = col; }
      }
  }
  __syncthreads();
  float* redv = &sx[0][0];
  int*   redi = (int*)&st[0][0];
  #pragma unroll
  for (int r = 0; r < 4; ++r) {
    int lrow = ty * 4 + r;
    redv[lrow * 16 + tx] = runMin[r];
    redi[lrow * 16 + tx] = runIdx[r];
  }
  __syncthreads();
  if (tid < 64) {
    float best = FLT_MAX; int bi = 0;
    #pragma unroll
    for (int j = 0; j < 16; ++j) {
      float v = redv[tid * 16 + j];
      int   i = redi[tid * 16 + j];
      if (v < best || (v == best && i < bi)) { best = v; bi = i; }
    }
    int grow = row0 + tid;
    pmin[(size_t)grow * S_STRIPS + strip] = best;
    pidx[(size_t)grow * S_STRIPS + strip] = bi;
  }
}

__global__ __launch_bounds__(256) void reduce_final_fb(
    const float* __restrict__ pmin, const int* __restrict__ pidx,
    float* __restrict__ out) {
  int row = blockIdx.x * 256 + threadIdx.x;
  if (row >= N_ROWS) return;
  float best = FLT_MAX; int bi = 0;
  #pragma unroll 4
  for (int s = 0; s < S_STRIPS; ++s) {
    float v = pmin[(size_t)row * S_STRIPS + s];
    int   i = pidx[(size_t)row * S_STRIPS + s];
    if (v < best || (v == best && i < bi)) { best = v; bi = i; }
  }
  out[row] = sqrtf(fmaxf(best, 0.0f));
  out[N_ROWS + row] = (float)bi;
}

// ---------------------------------------------------------------------------
extern "C" void kernel_launch(void* const* d_in, const int* in_sizes, int n_in,
                              void* d_out, int out_size, void* d_ws, size_t ws_size,
                              hipStream_t stream) {
  const float* x = (const float*)d_in[0];
  const float* t = (const float*)d_in[1];
  float* ws = (float*)d_ws;
  float* out = (float*)d_out;

  float* xn = ws;                       // 4096
  float* tn = ws + N_ROWS;              // 65536

  // fast-path ws layout (floats): xn | tn | bmv2[256*4096*2] | xb | tb
  const size_t f_bmv = (size_t)N_ROWS + M_TGT;
  const size_t f_xb  = f_bmv + (size_t)N_ROWS * NCB;
  const size_t f_tb  = f_xb + ((size_t)N_ROWS * DDIM) / 2;       // bf16 halves
  const size_t need_bytes = (f_tb + ((size_t)M_TGT * DDIM) / 2) * sizeof(float);

  if (ws_size >= need_bytes) {
    float* bmv2 = ws + f_bmv;
    unsigned short* xb = (unsigned short*)(ws + f_xb);
    unsigned short* tb = (unsigned short*)(ws + f_tb);

    conv_norm_kernel<<<(N_ROWS + 3) / 4, 256, 0, stream>>>(x, xb, xn, N_ROWS);
    conv_norm_kernel<<<(M_TGT + 3) / 4, 256, 0, stream>>>(t, tb, tn, M_TGT);

    nn_gemm_bf16<<<(N_ROWS / TBM) * (M_TGT / TBN), 512, 0, stream>>>(xb, tb, tn, bmv2);

    nn_exact<<<N_ROWS, 256, 0, stream>>>(x, t, xn, tn, bmv2, out);
  } else {
    norms_kernel_fb<<<(N_ROWS + M_TGT) / 4, 256, 0, stream>>>(x, t, xn, tn);
    float* pmin = ws + N_ROWS + M_TGT;
    int*   pidx = (int*)(ws + N_ROWS + M_TGT + (size_t)N_ROWS * S_STRIPS);
    dim3 grid(N_ROWS / BM, S_STRIPS);
    nn_main_fb<<<grid, 256, 0, stream>>>(x, t, xn, tn, pmin, pidx);
    reduce_final_fb<<<(N_ROWS + 255) / 256, 256, 0, stream>>>(pmin, pidx, out);
  }
}

// Round 5
// 301.689 us; speedup vs baseline: 1.0041x; 1.0041x over previous
//
#include <hip/hip_runtime.h>
#include <float.h>
#include <math.h>

#define N_ROWS 4096
#define M_TGT  65536
#define DDIM   256

// ---------------------------------------------------------------------------
// Shared types/helpers
// ---------------------------------------------------------------------------
typedef short bf16x8 __attribute__((ext_vector_type(8)));
typedef float f32x4 __attribute__((ext_vector_type(4)));
typedef unsigned short ushort4_t __attribute__((ext_vector_type(4)));

__device__ inline unsigned short f2bf(float f) {
  union { float f; unsigned u; } c; c.f = f;
  unsigned u = c.u;
  unsigned r = (u + 0x7FFFu + ((u >> 16) & 1u)) >> 16;  // RNE
  return (unsigned short)r;
}

__device__ inline void gload_lds16(const void* g, void* l) {
  __builtin_amdgcn_global_load_lds(
      (const __attribute__((address_space(1))) void*)g,
      (__attribute__((address_space(3))) void*)l, 16, 0, 0);
}

// ---------------------------------------------------------------------------
// Fused fp32->bf16 convert + row norm. One wave per row.
// ---------------------------------------------------------------------------
__global__ __launch_bounds__(256) void conv_norm_kernel(
    const float* __restrict__ src, unsigned short* __restrict__ dst,
    float* __restrict__ nrm, int nrows) {
  int wave = threadIdx.x >> 6;
  int lane = threadIdx.x & 63;
  int row  = blockIdx.x * 4 + wave;
  if (row >= nrows) return;
  const float* s = src + (size_t)row * DDIM;
  float4 v = *(const float4*)(s + lane * 4);
  float ss = v.x * v.x + v.y * v.y + v.z * v.z + v.w * v.w;
  ushort4_t o;
  o[0] = f2bf(v.x); o[1] = f2bf(v.y); o[2] = f2bf(v.z); o[3] = f2bf(v.w);
  *(ushort4_t*)(dst + (size_t)row * DDIM + lane * 4) = o;
  #pragma unroll
  for (int off = 32; off > 0; off >>= 1) ss += __shfl_xor(ss, off, 64);
  if (lane == 0) nrm[row] = ss;
}

// ---------------------------------------------------------------------------
// bf16 MFMA screening GEMM — m201-style 8-phase schedule.
// 256x256 tile, 8 waves (2M x 4N), BK=64, K=256 -> 4 K-steps.
// Each K-step = 4 phases of exactly 16 MFMA: {ds_read subtile | stage
// half-tile | s_barrier | lgkmcnt(0)+sched_barrier | setprio MFMA cluster |
// s_barrier}. Stages for K-step t+1 issue 2-4 phases before their vmcnt wait.
// LDS: 2 buf x (A 256x64 + B 256x64) bf16 = 128 KB, 1 block/CU.
// Swizzle: 128B rows = 8x16B slots, phys p = s ^ (row&7) (0-conflict, r3).
// global_load_lds dest linear; source pre-permuted with same involution.
// ---------------------------------------------------------------------------
#define TBM 256
#define TBN 256
#define NCB 512                    // 128-col groups
#define MARGIN 1.5f

#define STAGE4(T, IDX)                                                        \
  { constexpr int mat_ = (IDX) >> 1;                                          \
    constexpr int h_ = (IDX) & 1;                                             \
    const unsigned short* gb_ = mat_ ? tb : xb;                               \
    const int t0_ = mat_ ? col0 : row0;                                       \
    char* lb_ = (char*)&sAB[(T) & 1][mat_][0] + h_ * 16384;                   \
    gload_lds16(gb_ + (size_t)(t0_ + h_ * 128 + rS) * DDIM + (T) * 64 + sS * 8, \
                lb_ + tid * 16);                                              \
    gload_lds16(gb_ + (size_t)(t0_ + h_ * 128 + 64 + rS) * DDIM + (T) * 64 + sS * 8, \
                lb_ + 8192 + tid * 16);                                       \
  }

#define RD_FRAGS(KK)                                                          \
  { _Pragma("unroll")                                                         \
    for (int m = 0; m < 8; ++m) {                                             \
      int r_ = wr * 128 + m * 16 + ln;                                        \
      int p_ = ((KK) * 4 + cg) ^ (r_ & 7);                                    \
      af[m] = *(const bf16x8*)(Ab + r_ * 128 + p_ * 16);                      \
    }                                                                         \
    _Pragma("unroll")                                                         \
    for (int n = 0; n < 4; ++n) {                                             \
      int r_ = wc * 64 + n * 16 + ln;                                         \
      int p_ = ((KK) * 4 + cg) ^ (r_ & 7);                                    \
      bfv[n] = *(const bf16x8*)(Bb + r_ * 128 + p_ * 16);                     \
    } }

#define MFMA_HALF(MLO)                                                        \
  { __builtin_amdgcn_s_setprio(1);                                            \
    _Pragma("unroll")                                                         \
    for (int m = (MLO); m < (MLO) + 4; ++m)                                   \
      _Pragma("unroll")                                                       \
      for (int n = 0; n < 4; ++n)                                             \
        acc[m][n] = __builtin_amdgcn_mfma_f32_16x16x32_bf16(                  \
            af[m], bfv[n], acc[m][n], 0, 0, 0);                               \
    __builtin_amdgcn_s_setprio(0);                                            \
    __builtin_amdgcn_sched_barrier(0); }

#define KSTEP(T, DOSTAGE, TS)                                                 \
  { const char* Ab = (const char*)&sAB[(T) & 1][0][0];                        \
    const char* Bb = (const char*)&sAB[(T) & 1][1][0];                        \
    bf16x8 af[8]; bf16x8 bfv[4];                                              \
    /* phase 1: kk=0 reads + 2 stages + MFMA m0..3 */                         \
    RD_FRAGS(0)                                                               \
    if (DOSTAGE) { STAGE4(TS, 0) STAGE4(TS, 1) }                              \
    __builtin_amdgcn_s_barrier();                                             \
    asm volatile("s_waitcnt lgkmcnt(0)" ::: "memory");                        \
    __builtin_amdgcn_sched_barrier(0);                                        \
    MFMA_HALF(0)                                                              \
    __builtin_amdgcn_s_barrier();                                             \
    /* phase 2: 2 stages + MFMA m4..7 */                                      \
    if (DOSTAGE) { STAGE4(TS, 2) STAGE4(TS, 3) }                              \
    MFMA_HALF(4)                                                              \
    __builtin_amdgcn_s_barrier();                                             \
    /* phase 3: kk=1 reads + MFMA m0..3 */                                    \
    RD_FRAGS(1)                                                               \
    __builtin_amdgcn_s_barrier();                                             \
    asm volatile("s_waitcnt lgkmcnt(0)" ::: "memory");                        \
    __builtin_amdgcn_sched_barrier(0);                                        \
    MFMA_HALF(0)                                                              \
    __builtin_amdgcn_s_barrier();                                             \
    /* phase 4: MFMA m4..7 */                                                 \
    MFMA_HALF(4)                                                              \
    __builtin_amdgcn_s_barrier();                                             \
  }

__global__ __launch_bounds__(512, 1) void nn_gemm_bf16(
    const unsigned short* __restrict__ xb, const unsigned short* __restrict__ tb,
    const float* __restrict__ tn, float* __restrict__ bmv2) {
  __shared__ __align__(16) unsigned short sAB[2][2][TBM * 64];  // 128 KB

  const int tid  = threadIdx.x;
  const int lane = tid & 63;
  const int wid  = tid >> 6;        // 0..7
  const int wr   = wid >> 2;        // 0..1 (M halves)
  const int wc   = wid & 3;         // 0..3 (N quarters)
  const int ln   = lane & 15;
  const int cg   = lane >> 4;

  // XCD-aware, B-panel-reuse ordering: 4096 = 8 xcd * (16 rb * 32 cb)
  const int bid = blockIdx.x;
  const int xcd = bid & 7;
  const int wgi = bid >> 3;
  const int rb  = wgi & 15;                  // fastest: reuse B col-panel in L2
  const int cb  = xcd * 32 + (wgi >> 4);     // 0..255
  const int row0 = rb * TBM;
  const int col0 = cb * TBN;

  // staging map: chunk q = j*512 + tid -> local row = q>>3, phys slot = q&7,
  // logical slot s = (q&7) ^ (row&7); j=1 adds 64 rows (same s).
  const int rS = tid >> 3;
  const int sS = (tid & 7) ^ ((tid >> 3) & 7);

  f32x4 acc[8][4];
  const f32x4 zero = {0.0f, 0.0f, 0.0f, 0.0f};
  #pragma unroll
  for (int m = 0; m < 8; ++m)
    #pragma unroll
    for (int n = 0; n < 4; ++n) acc[m][n] = zero;

  // prologue: stage K-steps 0 and 1 (16 gloads)
  STAGE4(0, 0) STAGE4(0, 1) STAGE4(0, 2) STAGE4(0, 3)
  STAGE4(1, 0) STAGE4(1, 1) STAGE4(1, 2) STAGE4(1, 3)
  asm volatile("s_waitcnt vmcnt(8)" ::: "memory");   // K0 ready, K1 in flight
  __builtin_amdgcn_sched_barrier(0);
  __builtin_amdgcn_s_barrier();

  KSTEP(0, false, 0)
  asm volatile("s_waitcnt vmcnt(0)" ::: "memory");   // K1 (prologue) ready
  __builtin_amdgcn_sched_barrier(0);
  __builtin_amdgcn_s_barrier();
  KSTEP(1, true, 2)                                  // stages K2 -> buf0
  asm volatile("s_waitcnt vmcnt(0)" ::: "memory");   // K2 ready
  __builtin_amdgcn_sched_barrier(0);
  __builtin_amdgcn_s_barrier();
  KSTEP(2, true, 3)                                  // stages K3 -> buf1
  asm volatile("s_waitcnt vmcnt(0)" ::: "memory");   // K3 ready
  __builtin_amdgcn_sched_barrier(0);
  __builtin_amdgcn_s_barrier();
  KSTEP(3, false, 0)

  // ---- epilogue: per-row min of (tn[col] - 2*dot) per 128-col group ----
  float tnc[4];
  #pragma unroll
  for (int n = 0; n < 4; ++n)
    tnc[n] = tn[col0 + wc * 64 + n * 16 + ln];

  __syncthreads();                       // safe to reuse LDS
  float* emin = (float*)&sAB[0][0][0];   // [4 wc][256 rows]

  #pragma unroll
  for (int m = 0; m < 8; ++m) {
    float bv[4];
    #pragma unroll
    for (int j = 0; j < 4; ++j) bv[j] = FLT_MAX;
    #pragma unroll
    for (int n = 0; n < 4; ++n)
      #pragma unroll
      for (int j = 0; j < 4; ++j)
        bv[j] = fminf(bv[j], tnc[n] - 2.0f * acc[m][n][j]);
    #pragma unroll
    for (int off = 1; off < 16; off <<= 1)
      #pragma unroll
      for (int j = 0; j < 4; ++j)
        bv[j] = fminf(bv[j], __shfl_xor(bv[j], off, 64));
    if (ln == 0) {
      int rbase = wr * 128 + m * 16 + cg * 4;
      #pragma unroll
      for (int j = 0; j < 4; ++j)
        emin[wc * 256 + rbase + j] = bv[j];
    }
  }
  __syncthreads();
  if (tid < 256) {
    float g0 = fminf(emin[0 * 256 + tid], emin[1 * 256 + tid]);
    float g1 = fminf(emin[2 * 256 + tid], emin[3 * 256 + tid]);
    float2 o; o.x = g0; o.y = g1;
    *(float2*)&bmv2[((size_t)cb * N_ROWS + row0 + tid) * 2] = o;
  }
}

// ---------------------------------------------------------------------------
// Per-row candidate selection + exact fp32 verification.
// ---------------------------------------------------------------------------
__global__ __launch_bounds__(256) void nn_exact(
    const float* __restrict__ x, const float* __restrict__ t,
    const float* __restrict__ xn, const float* __restrict__ tn,
    const float* __restrict__ bmv2, float* __restrict__ out) {
  __shared__ float sv[NCB];
  __shared__ int   clist[NCB];
  __shared__ int   cnt;
  __shared__ float wmin[4];
  __shared__ float rv[256];
  __shared__ int   ri[256];

  const int row = blockIdx.x;
  const int tid = threadIdx.x;

  if (tid == 0) cnt = 0;
  float lmin = FLT_MAX;
  {
    float2 v = *(const float2*)&bmv2[((size_t)tid * N_ROWS + row) * 2];
    sv[2 * tid]     = v.x;
    sv[2 * tid + 1] = v.y;
    lmin = fminf(v.x, v.y);
  }
  #pragma unroll
  for (int off = 32; off > 0; off >>= 1) lmin = fminf(lmin, __shfl_xor(lmin, off, 64));
  if ((tid & 63) == 0) wmin[tid >> 6] = lmin;
  __syncthreads();
  const float g = fminf(fminf(wmin[0], wmin[1]), fminf(wmin[2], wmin[3]));

  #pragma unroll
  for (int e = tid; e < NCB; e += 256) {
    if (sv[e] <= g + MARGIN) {
      int p = atomicAdd(&cnt, 1);
      clist[p] = e;
    }
  }
  __syncthreads();
  const int nc = cnt;

  float best = FLT_MAX;
  int   bidx = 0x7FFFFFFF;
  const float xnr = xn[row];
  const float* xrow = x + (size_t)row * DDIM;

  for (int ci = 0; ci < nc; ci += 2) {
    int slot = ci + (tid >> 7);
    if (slot < nc) {
      int col = clist[slot] * 128 + (tid & 127);
      const float* trow = t + (size_t)col * DDIM;
      float acc = 0.0f;
      for (int kq = 0; kq < DDIM; kq += 4) {
        float4 xv = *(const float4*)(xrow + kq);
        float4 tv = *(const float4*)(trow + kq);
        acc = fmaf(xv.x, tv.x, acc);
        acc = fmaf(xv.y, tv.y, acc);
        acc = fmaf(xv.z, tv.z, acc);
        acc = fmaf(xv.w, tv.w, acc);
      }
      float d2 = xnr + tn[col] - 2.0f * acc;
      if (d2 < best || (d2 == best && col < bidx)) { best = d2; bidx = col; }
    }
  }
  rv[tid] = best; ri[tid] = bidx;
  __syncthreads();
  for (int s = 128; s >= 1; s >>= 1) {
    if (tid < s) {
      float vo = rv[tid + s]; int io = ri[tid + s];
      if (vo < rv[tid] || (vo == rv[tid] && io < ri[tid])) { rv[tid] = vo; ri[tid] = io; }
    }
    __syncthreads();
  }
  if (tid == 0) {
    out[row] = sqrtf(fmaxf(rv[0], 0.0f));
    out[N_ROWS + row] = (float)ri[0];
  }
}

// ---------------------------------------------------------------------------
// Fallback fp32 path (if ws too small) — round-1 proven
// ---------------------------------------------------------------------------
#define BM 64
#define BN 64
#define KC 16
#define S_STRIPS 32
#define PADM 68

__global__ __launch_bounds__(256) void norms_kernel_fb(
    const float* __restrict__ x, const float* __restrict__ t,
    float* __restrict__ xn, float* __restrict__ tn) {
  int wave = threadIdx.x >> 6;
  int lane = threadIdx.x & 63;
  int row  = blockIdx.x * 4 + wave;
  const float* src; float* dst;
  if (row < N_ROWS) { src = x + (size_t)row * DDIM; dst = xn + row; }
  else {
    int r = row - N_ROWS;
    if (r >= M_TGT) return;
    src = t + (size_t)r * DDIM; dst = tn + r;
  }
  float4 v = *(const float4*)(src + lane * 4);
  float s = v.x * v.x + v.y * v.y + v.z * v.z + v.w * v.w;
  #pragma unroll
  for (int off = 32; off > 0; off >>= 1) s += __shfl_xor(s, off, 64);
  if (lane == 0) *dst = s;
}

__global__ __launch_bounds__(256) void nn_main_fb(
    const float* __restrict__ x, const float* __restrict__ t,
    const float* __restrict__ xn, const float* __restrict__ tn,
    float* __restrict__ pmin, int* __restrict__ pidx) {
  __shared__ float sx[KC][PADM];
  __shared__ float st[KC][PADM];
  const int tid = threadIdx.x;
  const int rb = blockIdx.x;
  const int strip = blockIdx.y;
  const int tx = tid & 15, ty = tid >> 4;
  const int row0 = rb * BM;
  const int col_start = strip * (M_TGT / S_STRIPS);
  const int ntiles = (M_TGT / S_STRIPS) / BN;
  const int srow = tid >> 2;
  const int kq = (tid & 3) * 4;

  float runMin[4]; int runIdx[4];
  #pragma unroll
  for (int r = 0; r < 4; ++r) { runMin[r] = FLT_MAX; runIdx[r] = 0; }
  float xnr[4];
  #pragma unroll
  for (int r = 0; r < 4; ++r) xnr[r] = xn[row0 + ty * 4 + r];

  for (int tile = 0; tile < ntiles; ++tile) {
    const int cbk = col_start + tile * BN;
    float acc[4][4];
    #pragma unroll
    for (int r = 0; r < 4; ++r)
      #pragma unroll
      for (int c = 0; c < 4; ++c) acc[r][c] = 0.0f;
    #pragma unroll 1
    for (int kc = 0; kc < DDIM; kc += KC) {
      float4 xv = *(const float4*)(x + (size_t)(row0 + srow) * DDIM + kc + kq);
      float4 tv = *(const float4*)(t + (size_t)(cbk + srow) * DDIM + kc + kq);
      __syncthreads();
      sx[kq + 0][srow] = xv.x; sx[kq + 1][srow] = xv.y;
      sx[kq + 2][srow] = xv.z; sx[kq + 3][srow] = xv.w;
      st[kq + 0][srow] = tv.x; st[kq + 1][srow] = tv.y;
      st[kq + 2][srow] = tv.z; st[kq + 3][srow] = tv.w;
      __syncthreads();
      #pragma unroll
      for (int k = 0; k < KC; ++k) {
        float4 xa = *(const float4*)&sx[k][ty * 4];
        float4 tb2 = *(const float4*)&st[k][tx * 4];
        float xr[4] = {xa.x, xa.y, xa.z, xa.w};
        float tc[4] = {tb2.x, tb2.y, tb2.z, tb2.w};
        #pragma unroll
        for (int r = 0; r < 4; ++r)
          #pragma unroll
          for (int c = 0; c < 4; ++c)
            acc[r][c] = fmaf(xr[r], tc[c], acc[r][c]);
      }
    }
    #pragma unroll
    for (int r = 0; r < 4; ++r)
      #pragma unroll
      for (int c = 0; c < 4; ++c) {
        int col = cbk + tx * 4 + c;
        float d2 = xnr[r] + tn[col] - 2.0f * acc[r][c];
        if (d2 < runMin[r]) { runMin[r] = d2; runIdx[r] = col; }
      }
  }
  __syncthreads();
  float* redv = &sx[0][0];
  int*   redi = (int*)&st[0][0];
  #pragma unroll
  for (int r = 0; r < 4; ++r) {
    int lrow = ty * 4 + r;
    redv[lrow * 16 + tx] = runMin[r];
    redi[lrow * 16 + tx] = runIdx[r];
  }
  __syncthreads();
  if (tid < 64) {
    float best = FLT_MAX; int bi = 0;
    #pragma unroll
    for (int j = 0; j < 16; ++j) {
      float v = redv[tid * 16 + j];
      int   i = redi[tid * 16 + j];
      if (v < best || (v == best && i < bi)) { best = v; bi = i; }
    }
    int grow = row0 + tid;
    pmin[(size_t)grow * S_STRIPS + strip] = best;
    pidx[(size_t)grow * S_STRIPS + strip] = bi;
  }
}

__global__ __launch_bounds__(256) void reduce_final_fb(
    const float* __restrict__ pmin, const int* __restrict__ pidx,
    float* __restrict__ out) {
  int row = blockIdx.x * 256 + threadIdx.x;
  if (row >= N_ROWS) return;
  float best = FLT_MAX; int bi = 0;
  #pragma unroll 4
  for (int s = 0; s < S_STRIPS; ++s) {
    float v = pmin[(size_t)row * S_STRIPS + s];
    int   i = pidx[(size_t)row * S_STRIPS + s];
    if (v < best || (v == best && i < bi)) { best = v; bi = i; }
  }
  out[row] = sqrtf(fmaxf(best, 0.0f));
  out[N_ROWS + row] = (float)bi;
}

// ---------------------------------------------------------------------------
extern "C" void kernel_launch(void* const* d_in, const int* in_sizes, int n_in,
                              void* d_out, int out_size, void* d_ws, size_t ws_size,
                              hipStream_t stream) {
  const float* x = (const float*)d_in[0];
  const float* t = (const float*)d_in[1];
  float* ws = (float*)d_ws;
  float* out = (float*)d_out;

  float* xn = ws;                       // 4096
  float* tn = ws + N_ROWS;              // 65536

  // fast-path ws layout (floats): xn | tn | bmv2[256*4096*2] | xb | tb
  const size_t f_bmv = (size_t)N_ROWS + M_TGT;
  const size_t f_xb  = f_bmv + (size_t)N_ROWS * NCB;
  const size_t f_tb  = f_xb + ((size_t)N_ROWS * DDIM) / 2;       // bf16 halves
  const size_t need_bytes = (f_tb + ((size_t)M_TGT * DDIM) / 2) * sizeof(float);

  if (ws_size >= need_bytes) {
    float* bmv2 = ws + f_bmv;
    unsigned short* xb = (unsigned short*)(ws + f_xb);
    unsigned short* tb = (unsigned short*)(ws + f_tb);

    conv_norm_kernel<<<(N_ROWS + 3) / 4, 256, 0, stream>>>(x, xb, xn, N_ROWS);
    conv_norm_kernel<<<(M_TGT + 3) / 4, 256, 0, stream>>>(t, tb, tn, M_TGT);

    nn_gemm_bf16<<<(N_ROWS / TBM) * (M_TGT / TBN), 512, 0, stream>>>(xb, tb, tn, bmv2);

    nn_exact<<<N_ROWS, 256, 0, stream>>>(x, t, xn, tn, bmv2, out);
  } else {
    norms_kernel_fb<<<(N_ROWS + M_TGT) / 4, 256, 0, stream>>>(x, t, xn, tn);
    float* pmin = ws + N_ROWS + M_TGT;
    int*   pidx = (int*)(ws + N_ROWS + M_TGT + (size_t)N_ROWS * S_STRIPS);
    dim3 grid(N_ROWS / BM, S_STRIPS);
    nn_main_fb<<<grid, 256, 0, stream>>>(x, t, xn, tn, pmin, pidx);
    reduce_final_fb<<<(N_ROWS + 255) / 256, 256, 0, stream>>>(pmin, pidx, out);
  }
}